// Round 1
// baseline (1506.186 us; speedup 1.0000x reference)
//
#include <hip/hip_runtime.h>
#include <hip/hip_bf16.h>
#include <math.h>

#define HEADS 8
#define HEAD_DIM 32
#define DIM 256
#define MLP_DIM 1024
#define NTOK 4096
#define BATCH 8
#define M_TOK (BATCH*NTOK)
#define CELL_DIM 15
#define PE_IN 3
#define UPD 12

static __device__ __forceinline__ float bf2f(unsigned short u) {
    return __uint_as_float(((unsigned int)u) << 16);
}
static __device__ __forceinline__ unsigned short f2bf(float f) {
    __hip_bfloat16 h = __float2bfloat16(f);
    union { __hip_bfloat16 h; unsigned short u; } cv; cv.h = h; return cv.u;
}

// x[tok,d] = sum_c cells[b,c,n]*We[c,d] + be[d] + pe[n,d]
__global__ __launch_bounds__(256) void k_embed(const float* __restrict__ cells,
        const float* __restrict__ We, const float* __restrict__ be,
        float* __restrict__ x) {
    int tok = blockIdx.x;
    int d = threadIdx.x;
    int b = tok >> 12, n = tok & 4095;
    const float* cb = cells + (size_t)b * CELL_DIM * NTOK + n;
    float acc = 0.f;
#pragma unroll
    for (int c = 0; c < CELL_DIM; ++c)
        acc += cb[c * NTOK] * We[c * DIM + d];
    int i = d >> 1;
    float freq = expf(-logf(10000.f) * (float)(2 * i) / (float)DIM);
    float ph = (float)n * freq;
    float pe = (d & 1) ? cosf(ph) : sinf(ph);
    x[(size_t)tok * DIM + d] = acc + be[d] + pe;
}

// wave-per-token LayerNorm, f32 in -> bf16 out
__global__ __launch_bounds__(256) void k_ln(const float* __restrict__ x,
        const float* __restrict__ g, const float* __restrict__ bsh,
        unsigned short* __restrict__ y) {
    int wave = threadIdx.x >> 6, lane = threadIdx.x & 63;
    int tok = blockIdx.x * 4 + wave;
    const float4* xr = (const float4*)(x + (size_t)tok * DIM);
    float4 v = xr[lane];
    float s = v.x + v.y + v.z + v.w;
    float ss = v.x * v.x + v.y * v.y + v.z * v.z + v.w * v.w;
#pragma unroll
    for (int off = 32; off; off >>= 1) { s += __shfl_xor(s, off); ss += __shfl_xor(ss, off); }
    float mean = s * (1.f / DIM);
    float var = ss * (1.f / DIM) - mean * mean;
    float rstd = rsqrtf(var + 1e-5f);
    float4 gg = ((const float4*)g)[lane];
    float4 bb = ((const float4*)bsh)[lane];
    ushort4 o;
    o.x = f2bf((v.x - mean) * rstd * gg.x + bb.x);
    o.y = f2bf((v.y - mean) * rstd * gg.y + bb.y);
    o.z = f2bf((v.z - mean) * rstd * gg.z + bb.z);
    o.w = f2bf((v.w - mean) * rstd * gg.w + bb.w);
    ((ushort4*)(y + (size_t)tok * DIM))[lane] = o;
}

static __device__ __forceinline__ float gelu_exact(float v) {
    return v * 0.5f * (1.f + erff(v * 0.70710678118f));
}

// C[M,N] = A[M,K](bf16) @ B[K,N](f32) + epilogue
// EPI 0: +bias(optional) -> bf16 out
// EPI 1: gelu(+bias) -> bf16 out
// EPI 2: +bias +resid -> f32 out
template<int EPI>
__global__ __launch_bounds__(256) void k_gemm(const unsigned short* __restrict__ A,
        const float* __restrict__ B, const float* __restrict__ bias,
        const float* __restrict__ resid, void* __restrict__ Cout,
        int M, int N, int K) {
    __shared__ float As[16][68];
    __shared__ float Bs[16][68];
    int tx = threadIdx.x & 15, ty = threadIdx.x >> 4;
    int n0 = blockIdx.x * 64, m0 = blockIdx.y * 64;
    float c[4][4] = {};
    for (int k0 = 0; k0 < K; k0 += 16) {
        {
            int m = threadIdx.x >> 2, kq = (threadIdx.x & 3) * 4;
            ushort4 a4 = *(const ushort4*)(A + (size_t)(m0 + m) * K + k0 + kq);
            As[kq + 0][m] = bf2f(a4.x);
            As[kq + 1][m] = bf2f(a4.y);
            As[kq + 2][m] = bf2f(a4.z);
            As[kq + 3][m] = bf2f(a4.w);
            int r = threadIdx.x >> 4, cq = (threadIdx.x & 15) * 4;
            float4 b4 = *(const float4*)(B + (size_t)(k0 + r) * N + n0 + cq);
            *(float4*)&Bs[r][cq] = b4;
        }
        __syncthreads();
#pragma unroll
        for (int k = 0; k < 16; ++k) {
            float4 a = *(const float4*)&As[k][ty * 4];
            float4 b = *(const float4*)&Bs[k][tx * 4];
            float av[4] = {a.x, a.y, a.z, a.w};
            float bv[4] = {b.x, b.y, b.z, b.w};
#pragma unroll
            for (int i = 0; i < 4; ++i)
#pragma unroll
                for (int j = 0; j < 4; ++j)
                    c[i][j] += av[i] * bv[j];
        }
        __syncthreads();
    }
    float bv[4];
#pragma unroll
    for (int j = 0; j < 4; ++j) bv[j] = bias ? bias[n0 + tx * 4 + j] : 0.f;
#pragma unroll
    for (int i = 0; i < 4; ++i) {
        int row = m0 + ty * 4 + i;
        if (EPI == 2) {
            float4 r4 = *(const float4*)(resid + (size_t)row * N + n0 + tx * 4);
            float4 o;
            o.x = c[i][0] + bv[0] + r4.x;
            o.y = c[i][1] + bv[1] + r4.y;
            o.z = c[i][2] + bv[2] + r4.z;
            o.w = c[i][3] + bv[3] + r4.w;
            *(float4*)((float*)Cout + (size_t)row * N + n0 + tx * 4) = o;
        } else {
            float v0 = c[i][0] + bv[0], v1 = c[i][1] + bv[1];
            float v2 = c[i][2] + bv[2], v3 = c[i][3] + bv[3];
            if (EPI == 1) { v0 = gelu_exact(v0); v1 = gelu_exact(v1); v2 = gelu_exact(v2); v3 = gelu_exact(v3); }
            ushort4 o;
            o.x = f2bf(v0); o.y = f2bf(v1); o.z = f2bf(v2); o.w = f2bf(v3);
            *(ushort4*)((unsigned short*)Cout + (size_t)row * N + n0 + tx * 4) = o;
        }
    }
}

// block-per-token local 3x3 attention. qkv [tok,768] bf16, out [tok,256] bf16
__global__ __launch_bounds__(256) void k_attn(const unsigned short* __restrict__ qkv,
        unsigned short* __restrict__ out) {
    int tok = blockIdx.x;
    int t = threadIdx.x;
    int h = t >> 5, d = t & 31;
    int b = tok >> 12, n = tok & 4095;
    int r = n >> 6, cidx = n & 63;
    float q = bf2f(qkv[(size_t)tok * 768 + h * 32 + d]);
    float dots[9], vv[9];
#pragma unroll
    for (int ki = 0; ki < 3; ++ki)
#pragma unroll
        for (int kj = 0; kj < 3; ++kj) {
            int rr = (r + ki - 1) & 63, cc = (cidx + kj - 1) & 63;
            int nt = (b << 12) + (rr << 6) + cc;
            float kv = bf2f(qkv[(size_t)nt * 768 + 256 + h * 32 + d]);
            float p = q * kv;
#pragma unroll
            for (int off = 16; off; off >>= 1) p += __shfl_xor(p, off);
            dots[ki * 3 + kj] = p * 0.17677669529f;
            vv[ki * 3 + kj] = bf2f(qkv[(size_t)nt * 768 + 512 + h * 32 + d]);
        }
    float m = dots[0];
#pragma unroll
    for (int j = 1; j < 9; ++j) m = fmaxf(m, dots[j]);
    float sum = 0.f, w[9];
#pragma unroll
    for (int j = 0; j < 9; ++j) { w[j] = __expf(dots[j] - m); sum += w[j]; }
    float inv = 1.f / sum;
    float o = 0.f;
#pragma unroll
    for (int j = 0; j < 9; ++j) o += w[j] * vv[j];
    out[(size_t)tok * 256 + h * 32 + d] = f2bf(o * inv);
}

// head: LN(x) @ Wh + bh, assemble output [b,15,64,64]
__global__ __launch_bounds__(256) void k_head(const float* __restrict__ x,
        const float* __restrict__ g, const float* __restrict__ bln,
        const float* __restrict__ Wh, const float* __restrict__ bh,
        const float* __restrict__ cells, float* __restrict__ outp) {
    __shared__ float sh[DIM];
    __shared__ float red[8];
    int tok = blockIdx.x;
    int t = threadIdx.x;
    float v = x[(size_t)tok * DIM + t];
    float s = v, ss = v * v;
#pragma unroll
    for (int off = 32; off; off >>= 1) { s += __shfl_xor(s, off); ss += __shfl_xor(ss, off); }
    int wave = t >> 6, lane = t & 63;
    if (lane == 0) { red[wave] = s; red[4 + wave] = ss; }
    __syncthreads();
    float stot = red[0] + red[1] + red[2] + red[3];
    float sstot = red[4] + red[5] + red[6] + red[7];
    float mean = stot * (1.f / DIM);
    float rstd = rsqrtf(sstot * (1.f / DIM) - mean * mean + 1e-5f);
    sh[t] = (v - mean) * rstd * g[t] + bln[t];
    __syncthreads();
    int b = tok >> 12, n = tok & 4095;
    if (t < UPD) {
        float acc = bh[t];
        for (int k = 0; k < DIM; ++k) acc += sh[k] * Wh[k * UPD + t];
        size_t ci = (size_t)b * CELL_DIM * NTOK + (size_t)(PE_IN + t) * NTOK + n;
        outp[ci] = cells[ci] + acc;
    } else if (t < CELL_DIM) {
        size_t ci = (size_t)b * CELL_DIM * NTOK + (size_t)(t - UPD) * NTOK + n;
        outp[ci] = cells[ci];
    }
}

extern "C" void kernel_launch(void* const* d_in, const int* in_sizes, int n_in,
                              void* d_out, int out_size, void* d_ws, size_t ws_size,
                              hipStream_t stream) {
    const float* cells = (const float*)d_in[0];
    const float* We    = (const float*)d_in[1];
    const float* be    = (const float*)d_in[2];
    const float* ln1_g = (const float*)d_in[3];
    const float* ln1_b = (const float*)d_in[4];
    const float* Wqkv  = (const float*)d_in[5];
    const float* Wo    = (const float*)d_in[6];
    const float* bo    = (const float*)d_in[7];
    const float* ln2_g = (const float*)d_in[8];
    const float* ln2_b = (const float*)d_in[9];
    const float* W1    = (const float*)d_in[10];
    const float* b1    = (const float*)d_in[11];
    const float* W2    = (const float*)d_in[12];
    const float* b2    = (const float*)d_in[13];
    const float* lnh_g = (const float*)d_in[14];
    const float* lnh_b = (const float*)d_in[15];
    const float* Wh    = (const float*)d_in[16];
    const float* bh    = (const float*)d_in[17];
    float* outp = (float*)d_out;

    char* ws = (char*)d_ws;
    float* x = (float*)ws;                                   // 33.5 MB f32 residual stream
    unsigned short* y = (unsigned short*)(ws + 33554432);    // 16.8 MB bf16 LN-out / attn-out (aliased)
    unsigned short* scratch = (unsigned short*)(ws + 50331648); // 67 MB bf16 qkv / mlp-hidden (union)
    unsigned short* attnout = y;

    k_embed<<<M_TOK, 256, 0, stream>>>(cells, We, be, x);
    for (int l = 0; l < 2; ++l) {
        k_ln<<<M_TOK / 4, 256, 0, stream>>>(x, ln1_g + l * DIM, ln1_b + l * DIM, y);
        k_gemm<0><<<dim3(768 / 64, M_TOK / 64), 256, 0, stream>>>(
            y, Wqkv + (size_t)l * DIM * 768, nullptr, nullptr, scratch, M_TOK, 768, DIM);
        k_attn<<<M_TOK, 256, 0, stream>>>(scratch, attnout);
        k_gemm<2><<<dim3(256 / 64, M_TOK / 64), 256, 0, stream>>>(
            attnout, Wo + (size_t)l * DIM * DIM, bo + l * DIM, x, x, M_TOK, DIM, DIM);
        k_ln<<<M_TOK / 4, 256, 0, stream>>>(x, ln2_g + l * DIM, ln2_b + l * DIM, y);
        k_gemm<1><<<dim3(1024 / 64, M_TOK / 64), 256, 0, stream>>>(
            y, W1 + (size_t)l * DIM * MLP_DIM, b1 + l * MLP_DIM, nullptr, scratch, M_TOK, MLP_DIM, DIM);
        k_gemm<2><<<dim3(256 / 64, M_TOK / 64), 256, 0, stream>>>(
            scratch, W2 + (size_t)l * MLP_DIM * DIM, b2 + l * DIM, x, x, M_TOK, DIM, MLP_DIM);
    }
    k_head<<<M_TOK, 256, 0, stream>>>(x, lnh_g, lnh_b, Wh, bh, cells, outp);
}

// Round 2
// 563.016 us; speedup vs baseline: 2.6752x; 2.6752x over previous
//
#include <hip/hip_runtime.h>
#include <hip/hip_bf16.h>
#include <math.h>

#define HEADS 8
#define HEAD_DIM 32
#define DIM 256
#define MLP_DIM 1024
#define NTOK 4096
#define BATCH 8
#define M_TOK (BATCH*NTOK)
#define CELL_DIM 15
#define PE_IN 3
#define UPD 12

typedef __attribute__((ext_vector_type(8))) short bf16x8;
typedef __attribute__((ext_vector_type(4))) float f32x4;

static __device__ __forceinline__ float bf2f(unsigned short u) {
    return __uint_as_float(((unsigned int)u) << 16);
}
static __device__ __forceinline__ unsigned short f2bf(float f) {
    __hip_bfloat16 h = __float2bfloat16(f);
    union { __hip_bfloat16 h; unsigned short u; } cv; cv.h = h; return cv.u;
}
static __device__ __forceinline__ void gload_lds16(const unsigned short* g, unsigned short* l) {
    __builtin_amdgcn_global_load_lds(
        (const __attribute__((address_space(1))) void*)g,
        (__attribute__((address_space(3))) void*)l, 16, 0, 0);
}
static __device__ __forceinline__ float gelu_exact(float v) {
    return v * 0.5f * (1.f + erff(v * 0.70710678118f));
}

// x[tok,d] = sum_c cells[b,c,n]*We[c,d] + be[d] + pe[n,d]
__global__ __launch_bounds__(256) void k_embed(const float* __restrict__ cells,
        const float* __restrict__ We, const float* __restrict__ be,
        float* __restrict__ x) {
    int tok = blockIdx.x;
    int d = threadIdx.x;
    int b = tok >> 12, n = tok & 4095;
    const float* cb = cells + (size_t)b * CELL_DIM * NTOK + n;
    float acc = 0.f;
#pragma unroll
    for (int c = 0; c < CELL_DIM; ++c)
        acc += cb[c * NTOK] * We[c * DIM + d];
    int i = d >> 1;
    float freq = expf(-logf(10000.f) * (float)(2 * i) / (float)DIM);
    float ph = (float)n * freq;
    float pe = (d & 1) ? cosf(ph) : sinf(ph);
    x[(size_t)tok * DIM + d] = acc + be[d] + pe;
}

// wave-per-token LayerNorm, f32 in -> bf16 out
__global__ __launch_bounds__(256) void k_ln(const float* __restrict__ x,
        const float* __restrict__ g, const float* __restrict__ bsh,
        unsigned short* __restrict__ y) {
    int wave = threadIdx.x >> 6, lane = threadIdx.x & 63;
    int tok = blockIdx.x * 4 + wave;
    const float4* xr = (const float4*)(x + (size_t)tok * DIM);
    float4 v = xr[lane];
    float s = v.x + v.y + v.z + v.w;
    float ss = v.x * v.x + v.y * v.y + v.z * v.z + v.w * v.w;
#pragma unroll
    for (int off = 32; off; off >>= 1) { s += __shfl_xor(s, off); ss += __shfl_xor(ss, off); }
    float mean = s * (1.f / DIM);
    float var = ss * (1.f / DIM) - mean * mean;
    float rstd = rsqrtf(var + 1e-5f);
    float4 gg = ((const float4*)g)[lane];
    float4 bb = ((const float4*)bsh)[lane];
    ushort4 o;
    o.x = f2bf((v.x - mean) * rstd * gg.x + bb.x);
    o.y = f2bf((v.y - mean) * rstd * gg.y + bb.y);
    o.z = f2bf((v.z - mean) * rstd * gg.z + bb.z);
    o.w = f2bf((v.w - mean) * rstd * gg.w + bb.w);
    ((ushort4*)(y + (size_t)tok * DIM))[lane] = o;
}

// Transpose+convert all weights to bf16 [N,K] layout.
// wT per layer: qkvT[768x256]@0, WoT[256x256]@196608, W1T[1024x256]@262144, W2T[256x1024]@524288
__global__ __launch_bounds__(256) void k_prep(const float* __restrict__ Wqkv,
        const float* __restrict__ Wo, const float* __restrict__ W1,
        const float* __restrict__ W2, unsigned short* __restrict__ wT) {
    int seg = blockIdx.y;            // l*4 + mat
    int l = seg >> 2, mat = seg & 3;
    const float* src; int kwSh, Nw; size_t ooff;
    switch (mat) {
        case 0: src = Wqkv + (size_t)l * 196608; kwSh = 8;  Nw = 768;  ooff = (size_t)l * 786432 + 0;      break;
        case 1: src = Wo   + (size_t)l * 65536;  kwSh = 8;  Nw = 256;  ooff = (size_t)l * 786432 + 196608; break;
        case 2: src = W1   + (size_t)l * 262144; kwSh = 8;  Nw = 1024; ooff = (size_t)l * 786432 + 262144; break;
        default:src = W2   + (size_t)l * 262144; kwSh = 10; Nw = 256;  ooff = (size_t)l * 786432 + 524288; break;
    }
    int Kw = 1 << kwSh;
    int total = Kw * Nw;
    int idx = blockIdx.x * 256 + threadIdx.x;
    if (idx >= total) return;
    int n = idx >> kwSh, k = idx & (Kw - 1);
    wT[ooff + idx] = f2bf(src[(size_t)k * Nw + n]);
}

// MFMA GEMM: C[M,N] = A[M,K](bf16) @ BT[N,K](bf16)^T + epilogue
// EPI 0: (+bias) -> bf16 ; EPI 1: gelu(+bias) -> bf16 ; EPI 2: +bias +resid -> f32
template<int EPI>
__global__ __launch_bounds__(256) void k_mgemm(const unsigned short* __restrict__ A,
        const unsigned short* __restrict__ BT, const float* __restrict__ bias,
        const float* __restrict__ resid, void* __restrict__ Cout,
        int M, int N, int K) {
    __shared__ unsigned short As[128 * 32];   // 8 KB, [128 rows][32 k]
    __shared__ unsigned short Bs[128 * 32];   // 8 KB
    int t = threadIdx.x;
    int lane = t & 63, w = t >> 6;
    int wm = (w >> 1) * 64, wn = (w & 1) * 64;
    int m0 = blockIdx.y * 128, n0 = blockIdx.x * 128;

    f32x4 acc[4][4] = {};

    int srow = t >> 2;                 // 0..63
    int scol = (t & 3) * 8;
    const unsigned short* aBase = A  + (size_t)(m0 + srow) * K + scol;
    const unsigned short* bBase = BT + (size_t)(n0 + srow) * K + scol;
    unsigned short* aDst = As + t * 8;
    unsigned short* bDst = Bs + t * 8;
    int fr = lane & 15, kb = (lane >> 4) * 8;

    for (int k0 = 0; k0 < K; k0 += 32) {
        gload_lds16(aBase + k0,          aDst);
        gload_lds16(aBase + 64 * K + k0, aDst + 2048);
        gload_lds16(bBase + k0,          bDst);
        gload_lds16(bBase + 64 * K + k0, bDst + 2048);
        __syncthreads();
        bf16x8 af[4], bfv[4];
#pragma unroll
        for (int i = 0; i < 4; ++i)
            af[i] = *(const bf16x8*)&As[(wm + i * 16 + fr) * 32 + kb];
#pragma unroll
        for (int j = 0; j < 4; ++j)
            bfv[j] = *(const bf16x8*)&Bs[(wn + j * 16 + fr) * 32 + kb];
#pragma unroll
        for (int i = 0; i < 4; ++i)
#pragma unroll
            for (int j = 0; j < 4; ++j)
                acc[i][j] = __builtin_amdgcn_mfma_f32_16x16x32_bf16(af[i], bfv[j], acc[i][j], 0, 0, 0);
        __syncthreads();
    }

    int col = lane & 15;
    int rowq = (lane >> 4) * 4;
#pragma unroll
    for (int j = 0; j < 4; ++j) {
        int gcol = n0 + wn + j * 16 + col;
        float bv = bias ? bias[gcol] : 0.f;
#pragma unroll
        for (int i = 0; i < 4; ++i) {
#pragma unroll
            for (int r = 0; r < 4; ++r) {
                int grow = m0 + wm + i * 16 + rowq + r;
                float v = acc[i][j][r] + bv;
                if (EPI == 1) v = gelu_exact(v);
                if (EPI == 2) {
                    v += resid[(size_t)grow * N + gcol];
                    ((float*)Cout)[(size_t)grow * N + gcol] = v;
                } else {
                    ((unsigned short*)Cout)[(size_t)grow * N + gcol] = f2bf(v);
                }
            }
        }
    }
}

// block-per-token local 3x3 attention. qkv [tok,768] bf16, out [tok,256] bf16
__global__ __launch_bounds__(256) void k_attn(const unsigned short* __restrict__ qkv,
        unsigned short* __restrict__ out) {
    int tok = blockIdx.x;
    int t = threadIdx.x;
    int h = t >> 5, d = t & 31;
    int b = tok >> 12, n = tok & 4095;
    int r = n >> 6, cidx = n & 63;
    float q = bf2f(qkv[(size_t)tok * 768 + h * 32 + d]);
    float dots[9], vv[9];
#pragma unroll
    for (int ki = 0; ki < 3; ++ki)
#pragma unroll
        for (int kj = 0; kj < 3; ++kj) {
            int rr = (r + ki - 1) & 63, cc = (cidx + kj - 1) & 63;
            int nt = (b << 12) + (rr << 6) + cc;
            float kv = bf2f(qkv[(size_t)nt * 768 + 256 + h * 32 + d]);
            float p = q * kv;
#pragma unroll
            for (int off = 16; off; off >>= 1) p += __shfl_xor(p, off);
            dots[ki * 3 + kj] = p * 0.17677669529f;
            vv[ki * 3 + kj] = bf2f(qkv[(size_t)nt * 768 + 512 + h * 32 + d]);
        }
    float m = dots[0];
#pragma unroll
    for (int j = 1; j < 9; ++j) m = fmaxf(m, dots[j]);
    float sum = 0.f, wgt[9];
#pragma unroll
    for (int j = 0; j < 9; ++j) { wgt[j] = __expf(dots[j] - m); sum += wgt[j]; }
    float inv = 1.f / sum;
    float o = 0.f;
#pragma unroll
    for (int j = 0; j < 9; ++j) o += wgt[j] * vv[j];
    out[(size_t)tok * 256 + h * 32 + d] = f2bf(o * inv);
}

// head: LN(x) @ Wh + bh, assemble output [b,15,64,64]
__global__ __launch_bounds__(256) void k_head(const float* __restrict__ x,
        const float* __restrict__ g, const float* __restrict__ bln,
        const float* __restrict__ Wh, const float* __restrict__ bh,
        const float* __restrict__ cells, float* __restrict__ outp) {
    __shared__ float sh[DIM];
    __shared__ float red[8];
    int tok = blockIdx.x;
    int t = threadIdx.x;
    float v = x[(size_t)tok * DIM + t];
    float s = v, ss = v * v;
#pragma unroll
    for (int off = 32; off; off >>= 1) { s += __shfl_xor(s, off); ss += __shfl_xor(ss, off); }
    int wave = t >> 6, lane = t & 63;
    if (lane == 0) { red[wave] = s; red[4 + wave] = ss; }
    __syncthreads();
    float stot = red[0] + red[1] + red[2] + red[3];
    float sstot = red[4] + red[5] + red[6] + red[7];
    float mean = stot * (1.f / DIM);
    float rstd = rsqrtf(sstot * (1.f / DIM) - mean * mean + 1e-5f);
    sh[t] = (v - mean) * rstd * g[t] + bln[t];
    __syncthreads();
    int b = tok >> 12, n = tok & 4095;
    if (t < UPD) {
        float acc = bh[t];
        for (int k = 0; k < DIM; ++k) acc += sh[k] * Wh[k * UPD + t];
        size_t ci = (size_t)b * CELL_DIM * NTOK + (size_t)(PE_IN + t) * NTOK + n;
        outp[ci] = cells[ci] + acc;
    } else if (t < CELL_DIM) {
        size_t ci = (size_t)b * CELL_DIM * NTOK + (size_t)(t - UPD) * NTOK + n;
        outp[ci] = cells[ci];
    }
}

extern "C" void kernel_launch(void* const* d_in, const int* in_sizes, int n_in,
                              void* d_out, int out_size, void* d_ws, size_t ws_size,
                              hipStream_t stream) {
    const float* cells = (const float*)d_in[0];
    const float* We    = (const float*)d_in[1];
    const float* be    = (const float*)d_in[2];
    const float* ln1_g = (const float*)d_in[3];
    const float* ln1_b = (const float*)d_in[4];
    const float* Wqkv  = (const float*)d_in[5];
    const float* Wo    = (const float*)d_in[6];
    const float* bo    = (const float*)d_in[7];
    const float* ln2_g = (const float*)d_in[8];
    const float* ln2_b = (const float*)d_in[9];
    const float* W1    = (const float*)d_in[10];
    const float* b1    = (const float*)d_in[11];
    const float* W2    = (const float*)d_in[12];
    const float* b2    = (const float*)d_in[13];
    const float* lnh_g = (const float*)d_in[14];
    const float* lnh_b = (const float*)d_in[15];
    const float* Wh    = (const float*)d_in[16];
    const float* bh    = (const float*)d_in[17];
    float* outp = (float*)d_out;

    char* ws = (char*)d_ws;
    float* x = (float*)ws;                                        // 33.5 MB f32 residual
    unsigned short* y = (unsigned short*)(ws + 33554432);         // 16.8 MB bf16 LN-out / attn-out
    unsigned short* scratch = (unsigned short*)(ws + 50331648);   // 67 MB bf16 qkv / mlp-hidden
    unsigned short* wT = (unsigned short*)(ws + 117440512);       // 3.1 MB bf16 transposed weights
    unsigned short* attnout = y;

    k_prep<<<dim3(1024, 8), 256, 0, stream>>>(Wqkv, Wo, W1, W2, wT);
    k_embed<<<M_TOK, 256, 0, stream>>>(cells, We, be, x);
    for (int l = 0; l < 2; ++l) {
        const unsigned short* wL = wT + (size_t)l * 786432;
        k_ln<<<M_TOK / 4, 256, 0, stream>>>(x, ln1_g + l * DIM, ln1_b + l * DIM, y);
        k_mgemm<0><<<dim3(6, M_TOK / 128), 256, 0, stream>>>(
            y, wL + 0, nullptr, nullptr, scratch, M_TOK, 768, DIM);
        k_attn<<<M_TOK, 256, 0, stream>>>(scratch, attnout);
        k_mgemm<2><<<dim3(2, M_TOK / 128), 256, 0, stream>>>(
            attnout, wL + 196608, bo + l * DIM, x, x, M_TOK, DIM, DIM);
        k_ln<<<M_TOK / 4, 256, 0, stream>>>(x, ln2_g + l * DIM, ln2_b + l * DIM, y);
        k_mgemm<1><<<dim3(8, M_TOK / 128), 256, 0, stream>>>(
            y, wL + 262144, b1 + l * MLP_DIM, nullptr, scratch, M_TOK, MLP_DIM, DIM);
        k_mgemm<2><<<dim3(2, M_TOK / 128), 256, 0, stream>>>(
            scratch, wL + 524288, b2 + l * DIM, x, x, M_TOK, DIM, MLP_DIM);
    }
    k_head<<<M_TOK, 256, 0, stream>>>(x, lnh_g, lnh_b, Wh, bh, cells, outp);
}

// Round 3
// 493.315 us; speedup vs baseline: 3.0532x; 1.1413x over previous
//
#include <hip/hip_runtime.h>
#include <hip/hip_bf16.h>
#include <math.h>

#define HEADS 8
#define HEAD_DIM 32
#define DIM 256
#define MLP_DIM 1024
#define NTOK 4096
#define BATCH 8
#define M_TOK (BATCH*NTOK)
#define CELL_DIM 15
#define PE_IN 3
#define UPD 12

typedef __attribute__((ext_vector_type(8))) short bf16x8;
typedef __attribute__((ext_vector_type(4))) float f32x4;

static __device__ __forceinline__ float bf2f(unsigned short u) {
    return __uint_as_float(((unsigned int)u) << 16);
}
static __device__ __forceinline__ unsigned short f2bf(float f) {
    __hip_bfloat16 h = __float2bfloat16(f);
    union { __hip_bfloat16 h; unsigned short u; } cv; cv.h = h; return cv.u;
}
static __device__ __forceinline__ void gload_lds16(const unsigned short* g, unsigned short* l) {
    __builtin_amdgcn_global_load_lds(
        (const __attribute__((address_space(1))) void*)g,
        (__attribute__((address_space(3))) void*)l, 16, 0, 0);
}
static __device__ __forceinline__ float gelu_exact(float v) {
    return v * 0.5f * (1.f + erff(v * 0.70710678118f));
}

// embed + fused LN1[0]: x = cells@We + be + pe ; y = LN(x)
__global__ __launch_bounds__(256) void k_embed(const float* __restrict__ cells,
        const float* __restrict__ We, const float* __restrict__ be,
        const float* __restrict__ g, const float* __restrict__ bln,
        float* __restrict__ x, unsigned short* __restrict__ y) {
    __shared__ float red[8];
    int tok = blockIdx.x;
    int d = threadIdx.x;
    int b = tok >> 12, n = tok & 4095;
    const float* cb = cells + (size_t)b * CELL_DIM * NTOK + n;
    float acc = 0.f;
#pragma unroll
    for (int c = 0; c < CELL_DIM; ++c)
        acc += cb[c * NTOK] * We[c * DIM + d];
    int i = d >> 1;
    float freq = expf(-logf(10000.f) * (float)(2 * i) / (float)DIM);
    float ph = (float)n * freq;
    float pe = (d & 1) ? cosf(ph) : sinf(ph);
    float v = acc + be[d] + pe;
    x[(size_t)tok * DIM + d] = v;
    float s = v, ss = v * v;
#pragma unroll
    for (int off = 32; off; off >>= 1) { s += __shfl_xor(s, off); ss += __shfl_xor(ss, off); }
    int wave = d >> 6, lane = d & 63;
    if (lane == 0) { red[wave] = s; red[4 + wave] = ss; }
    __syncthreads();
    float stot = red[0] + red[1] + red[2] + red[3];
    float sstot = red[4] + red[5] + red[6] + red[7];
    float mean = stot * (1.f / DIM);
    float rstd = rsqrtf(sstot * (1.f / DIM) - mean * mean + 1e-5f);
    y[(size_t)tok * DIM + d] = f2bf((v - mean) * rstd * g[d] + bln[d]);
}

// Transpose+convert weights to bf16 [N,K]; seg 8 builds WhT [16x256] (rows 12-15 zero)
__global__ __launch_bounds__(256) void k_prep(const float* __restrict__ Wqkv,
        const float* __restrict__ Wo, const float* __restrict__ W1,
        const float* __restrict__ W2, const float* __restrict__ Wh,
        unsigned short* __restrict__ wT) {
    int seg = blockIdx.y;
    int idx = blockIdx.x * 256 + threadIdx.x;
    if (seg == 8) {
        if (idx >= 16 * 256) return;
        int u = idx >> 8, k = idx & 255;
        wT[1572864 + idx] = (u < UPD) ? f2bf(Wh[(size_t)k * UPD + u]) : (unsigned short)0;
        return;
    }
    int l = seg >> 2, mat = seg & 3;
    const float* src; int kwSh, Nw; size_t ooff;
    switch (mat) {
        case 0: src = Wqkv + (size_t)l * 196608; kwSh = 8;  Nw = 768;  ooff = (size_t)l * 786432 + 0;      break;
        case 1: src = Wo   + (size_t)l * 65536;  kwSh = 8;  Nw = 256;  ooff = (size_t)l * 786432 + 196608; break;
        case 2: src = W1   + (size_t)l * 262144; kwSh = 8;  Nw = 1024; ooff = (size_t)l * 786432 + 262144; break;
        default:src = W2   + (size_t)l * 262144; kwSh = 10; Nw = 256;  ooff = (size_t)l * 786432 + 524288; break;
    }
    int Kw = 1 << kwSh;
    if (idx >= Kw * Nw) return;
    int n = idx >> kwSh, k = idx & (Kw - 1);
    wT[ooff + idx] = f2bf(src[(size_t)k * Nw + n]);
}

// MFMA GEMM: C[M,N] = A[M,K](bf16) @ BT[N,K]^T + epi. EPI0: ->bf16 ; EPI1: gelu(+bias)->bf16
template<int EPI>
__global__ __launch_bounds__(256) void k_mgemm(const unsigned short* __restrict__ A,
        const unsigned short* __restrict__ BT, const float* __restrict__ bias,
        void* __restrict__ Cout, int M, int N, int K) {
    __shared__ unsigned short As[128 * 32];
    __shared__ unsigned short Bs[128 * 32];
    int t = threadIdx.x;
    int lane = t & 63, w = t >> 6;
    int wm = (w >> 1) * 64, wn = (w & 1) * 64;
    int m0 = blockIdx.y * 128, n0 = blockIdx.x * 128;

    f32x4 acc[4][4] = {};
    const unsigned short* aBase = A  + (size_t)(m0 + (t >> 2)) * K + (t & 3) * 8;
    const unsigned short* bBase = BT + (size_t)(n0 + (t >> 2)) * K + (t & 3) * 8;
    unsigned short* aDst = As + t * 8;
    unsigned short* bDst = Bs + t * 8;
    int fr = lane & 15, kb = (lane >> 4) * 8;

    for (int k0 = 0; k0 < K; k0 += 32) {
        gload_lds16(aBase + k0,          aDst);
        gload_lds16(aBase + 64 * K + k0, aDst + 2048);
        gload_lds16(bBase + k0,          bDst);
        gload_lds16(bBase + 64 * K + k0, bDst + 2048);
        __syncthreads();
        bf16x8 af[4], bfv[4];
#pragma unroll
        for (int i = 0; i < 4; ++i)
            af[i] = *(const bf16x8*)&As[(wm + i * 16 + fr) * 32 + kb];
#pragma unroll
        for (int j = 0; j < 4; ++j)
            bfv[j] = *(const bf16x8*)&Bs[(wn + j * 16 + fr) * 32 + kb];
#pragma unroll
        for (int i = 0; i < 4; ++i)
#pragma unroll
            for (int j = 0; j < 4; ++j)
                acc[i][j] = __builtin_amdgcn_mfma_f32_16x16x32_bf16(af[i], bfv[j], acc[i][j], 0, 0, 0);
        __syncthreads();
    }

    int col = lane & 15;
    int rowq = (lane >> 4) * 4;
#pragma unroll
    for (int j = 0; j < 4; ++j) {
        int gcol = n0 + wn + j * 16 + col;
        float bv = bias ? bias[gcol] : 0.f;
#pragma unroll
        for (int i = 0; i < 4; ++i) {
#pragma unroll
            for (int r = 0; r < 4; ++r) {
                int grow = m0 + wm + i * 16 + rowq + r;
                float v = acc[i][j][r] + bv;
                if (EPI == 1) v = gelu_exact(v);
                ((unsigned short*)Cout)[(size_t)grow * N + gcol] = f2bf(v);
            }
        }
    }
}

// Fused residual GEMM + LayerNorm, N==256 only. 512 threads, tile 128x256.
// x = A@BT + bias + x ; y = LN(x; g,b)
__global__ __launch_bounds__(512) void k_mgemm_ln(const unsigned short* __restrict__ A,
        const unsigned short* __restrict__ BT, const float* __restrict__ bias,
        const float* __restrict__ g, const float* __restrict__ bln,
        float* __restrict__ x, unsigned short* __restrict__ y, int K) {
    __shared__ unsigned short As[128 * 32];   // 8 KB
    __shared__ unsigned short Bs[256 * 32];   // 16 KB
    __shared__ float sred[128 * 4];
    __shared__ float ssred[128 * 4];
    __shared__ float msr[128 * 2];
    int t = threadIdx.x;
    int lane = t & 63, w = t >> 6;
    int wm = (w >> 2) * 64, wn = (w & 3) * 64, wnq = w & 3;
    int m0 = blockIdx.x * 128;

    f32x4 acc[4][4] = {};
    const unsigned short* aBase = A  + (size_t)(m0 + (t >> 2)) * K + (t & 3) * 8;
    const unsigned short* bBase = BT + (size_t)(t >> 2) * K + (t & 3) * 8;
    unsigned short* aDst = As + t * 8;
    unsigned short* bDst = Bs + t * 8;
    int fr = lane & 15, kb = (lane >> 4) * 8;

    for (int k0 = 0; k0 < K; k0 += 32) {
        gload_lds16(aBase + k0,           aDst);
        gload_lds16(bBase + k0,           bDst);
        gload_lds16(bBase + 128 * K + k0, bDst + 4096);
        __syncthreads();
        bf16x8 af[4], bfv[4];
#pragma unroll
        for (int i = 0; i < 4; ++i)
            af[i] = *(const bf16x8*)&As[(wm + i * 16 + fr) * 32 + kb];
#pragma unroll
        for (int j = 0; j < 4; ++j)
            bfv[j] = *(const bf16x8*)&Bs[(wn + j * 16 + fr) * 32 + kb];
#pragma unroll
        for (int i = 0; i < 4; ++i)
#pragma unroll
            for (int j = 0; j < 4; ++j)
                acc[i][j] = __builtin_amdgcn_mfma_f32_16x16x32_bf16(af[i], bfv[j], acc[i][j], 0, 0, 0);
        __syncthreads();
    }

    int col = lane & 15;
    int rowq = (lane >> 4) * 4;
    // add bias + residual into acc (acc becomes the final x values)
    float bv[4];
#pragma unroll
    for (int j = 0; j < 4; ++j) bv[j] = bias[wn + j * 16 + col];
#pragma unroll
    for (int i = 0; i < 4; ++i)
#pragma unroll
        for (int r = 0; r < 4; ++r) {
            int grow = m0 + wm + i * 16 + rowq + r;
#pragma unroll
            for (int j = 0; j < 4; ++j)
                acc[i][j][r] += bv[j] + x[(size_t)grow * DIM + wn + j * 16 + col];
        }
    // row partial sums (64 cols per wave) -> LDS
#pragma unroll
    for (int i = 0; i < 4; ++i)
#pragma unroll
        for (int r = 0; r < 4; ++r) {
            float s = acc[i][0][r] + acc[i][1][r] + acc[i][2][r] + acc[i][3][r];
            float ss = acc[i][0][r] * acc[i][0][r] + acc[i][1][r] * acc[i][1][r]
                     + acc[i][2][r] * acc[i][2][r] + acc[i][3][r] * acc[i][3][r];
#pragma unroll
            for (int off = 1; off < 16; off <<= 1) { s += __shfl_xor(s, off); ss += __shfl_xor(ss, off); }
            if ((lane & 15) == 0) {
                int row = wm + i * 16 + rowq + r;
                sred[row * 4 + wnq] = s;
                ssred[row * 4 + wnq] = ss;
            }
        }
    __syncthreads();
    if (t < 128) {
        float s = sred[t * 4] + sred[t * 4 + 1] + sred[t * 4 + 2] + sred[t * 4 + 3];
        float ss = ssred[t * 4] + ssred[t * 4 + 1] + ssred[t * 4 + 2] + ssred[t * 4 + 3];
        float mean = s * (1.f / DIM);
        float var = ss * (1.f / DIM) - mean * mean;
        msr[t * 2] = mean;
        msr[t * 2 + 1] = rsqrtf(var + 1e-5f);
    }
    __syncthreads();
    float gv[4], bb[4];
#pragma unroll
    for (int j = 0; j < 4; ++j) { gv[j] = g[wn + j * 16 + col]; bb[j] = bln[wn + j * 16 + col]; }
#pragma unroll
    for (int i = 0; i < 4; ++i)
#pragma unroll
        for (int r = 0; r < 4; ++r) {
            int row = wm + i * 16 + rowq + r;
            int grow = m0 + row;
            float mean = msr[row * 2], rstd = msr[row * 2 + 1];
#pragma unroll
            for (int j = 0; j < 4; ++j) {
                float v = acc[i][j][r];
                int gcol = wn + j * 16 + col;
                x[(size_t)grow * DIM + gcol] = v;
                y[(size_t)grow * DIM + gcol] = f2bf((v - mean) * rstd * gv[j] + bb[j]);
            }
        }
}

// block-per-token local 3x3 attention. qkv [tok,768] bf16, out [tok,256] bf16
__global__ __launch_bounds__(256) void k_attn(const unsigned short* __restrict__ qkv,
        unsigned short* __restrict__ out) {
    int tok = blockIdx.x;
    int t = threadIdx.x;
    int h = t >> 5, d = t & 31;
    int b = tok >> 12, n = tok & 4095;
    int r = n >> 6, cidx = n & 63;
    float q = bf2f(qkv[(size_t)tok * 768 + h * 32 + d]);
    float dots[9], vv[9];
#pragma unroll
    for (int ki = 0; ki < 3; ++ki)
#pragma unroll
        for (int kj = 0; kj < 3; ++kj) {
            int rr = (r + ki - 1) & 63, cc = (cidx + kj - 1) & 63;
            int nt = (b << 12) + (rr << 6) + cc;
            float kv = bf2f(qkv[(size_t)nt * 768 + 256 + h * 32 + d]);
            float p = q * kv;
#pragma unroll
            for (int off = 16; off; off >>= 1) p += __shfl_xor(p, off);
            dots[ki * 3 + kj] = p * 0.17677669529f;
            vv[ki * 3 + kj] = bf2f(qkv[(size_t)nt * 768 + 512 + h * 32 + d]);
        }
    float m = dots[0];
#pragma unroll
    for (int j = 1; j < 9; ++j) m = fmaxf(m, dots[j]);
    float sum = 0.f, wgt[9];
#pragma unroll
    for (int j = 0; j < 9; ++j) { wgt[j] = __expf(dots[j] - m); sum += wgt[j]; }
    float inv = 1.f / sum;
    float o = 0.f;
#pragma unroll
    for (int j = 0; j < 9; ++j) o += wgt[j] * vv[j];
    out[(size_t)tok * 256 + h * 32 + d] = f2bf(o * inv);
}

// head GEMV via MFMA: Cg[32768,16] = y[32768,256] @ WhT[16,256]^T
__global__ __launch_bounds__(256) void k_headgemv(const unsigned short* __restrict__ y,
        const unsigned short* __restrict__ WhT, float* __restrict__ Cg) {
    int t = threadIdx.x, lane = t & 63, w = t >> 6;
    int m0 = blockIdx.x * 64 + w * 16;
    int fr = lane & 15, kb = (lane >> 4) * 8;
    f32x4 acc = {};
    const unsigned short* aRow = y + (size_t)(m0 + fr) * DIM + kb;
    const unsigned short* bRow = WhT + (size_t)fr * DIM + kb;
#pragma unroll
    for (int k0 = 0; k0 < DIM; k0 += 32) {
        bf16x8 a = *(const bf16x8*)(aRow + k0);
        bf16x8 bfr = *(const bf16x8*)(bRow + k0);
        acc = __builtin_amdgcn_mfma_f32_16x16x32_bf16(a, bfr, acc, 0, 0, 0);
    }
    int col = lane & 15, rowq = (lane >> 4) * 4;
#pragma unroll
    for (int r = 0; r < 4; ++r)
        Cg[(size_t)(m0 + rowq + r) * 16 + col] = acc[r];
}

// out[b,c,n] = cells[b,c,n] + (c>=3 ? Cg[tok,c-3] + bh[c-3] : 0)
__global__ __launch_bounds__(256) void k_assemble(const float* __restrict__ cells,
        const float* __restrict__ Cg, const float* __restrict__ bh,
        float* __restrict__ outp) {
    int idx = blockIdx.x * 256 + threadIdx.x;
    int total = BATCH * CELL_DIM * (NTOK / 4);
    if (idx >= total) return;
    int n4 = idx & 1023;
    int c = (idx >> 10) % CELL_DIM;
    int b = idx / (CELL_DIM * 1024);
    size_t ci = ((size_t)b * CELL_DIM + c) * NTOK + n4 * 4;
    float4 o = *(const float4*)(cells + ci);
    if (c >= PE_IN) {
        int u = c - PE_IN;
        float bias = bh[u];
        size_t tok = (size_t)b * NTOK + n4 * 4;
        o.x += Cg[(tok + 0) * 16 + u] + bias;
        o.y += Cg[(tok + 1) * 16 + u] + bias;
        o.z += Cg[(tok + 2) * 16 + u] + bias;
        o.w += Cg[(tok + 3) * 16 + u] + bias;
    }
    *(float4*)(outp + ci) = o;
}

extern "C" void kernel_launch(void* const* d_in, const int* in_sizes, int n_in,
                              void* d_out, int out_size, void* d_ws, size_t ws_size,
                              hipStream_t stream) {
    const float* cells = (const float*)d_in[0];
    const float* We    = (const float*)d_in[1];
    const float* be    = (const float*)d_in[2];
    const float* ln1_g = (const float*)d_in[3];
    const float* ln1_b = (const float*)d_in[4];
    const float* Wqkv  = (const float*)d_in[5];
    const float* Wo    = (const float*)d_in[6];
    const float* bo    = (const float*)d_in[7];
    const float* ln2_g = (const float*)d_in[8];
    const float* ln2_b = (const float*)d_in[9];
    const float* W1    = (const float*)d_in[10];
    const float* b1    = (const float*)d_in[11];
    const float* W2    = (const float*)d_in[12];
    const float* b2    = (const float*)d_in[13];
    const float* lnh_g = (const float*)d_in[14];
    const float* lnh_b = (const float*)d_in[15];
    const float* Wh    = (const float*)d_in[16];
    const float* bh    = (const float*)d_in[17];
    float* outp = (float*)d_out;

    char* ws = (char*)d_ws;
    float* x = (float*)ws;                                        // 33.5 MB f32 residual
    unsigned short* y = (unsigned short*)(ws + 33554432);         // 16.8 MB bf16 LN-out / attn-out
    unsigned short* scratch = (unsigned short*)(ws + 50331648);   // 67 MB bf16 qkv / mlp-hidden
    unsigned short* wT = (unsigned short*)(ws + 117440512);       // 3 MB + 8KB transposed weights (incl WhT)
    unsigned short* attnout = y;
    float* Cg = (float*)scratch;                                  // reuse after last mlp2

    k_prep<<<dim3(1024, 9), 256, 0, stream>>>(Wqkv, Wo, W1, W2, Wh, wT);
    k_embed<<<M_TOK, 256, 0, stream>>>(cells, We, be, ln1_g, ln1_b, x, y);
    for (int l = 0; l < 2; ++l) {
        const unsigned short* wL = wT + (size_t)l * 786432;
        const float* gN = (l == 0) ? ln1_g + DIM : lnh_g;
        const float* bN = (l == 0) ? ln1_b + DIM : lnh_b;
        k_mgemm<0><<<dim3(6, M_TOK / 128), 256, 0, stream>>>(
            y, wL + 0, nullptr, scratch, M_TOK, 768, DIM);
        k_attn<<<M_TOK, 256, 0, stream>>>(scratch, attnout);
        k_mgemm_ln<<<M_TOK / 128, 512, 0, stream>>>(
            attnout, wL + 196608, bo + l * DIM, ln2_g + l * DIM, ln2_b + l * DIM, x, y, DIM);
        k_mgemm<1><<<dim3(8, M_TOK / 128), 256, 0, stream>>>(
            y, wL + 262144, b1 + l * MLP_DIM, scratch, M_TOK, MLP_DIM, DIM);
        k_mgemm_ln<<<M_TOK / 128, 512, 0, stream>>>(
            scratch, wL + 524288, b2 + l * DIM, gN, bN, x, y, MLP_DIM);
    }
    k_headgemv<<<M_TOK / 64, 256, 0, stream>>>(y, wT + 1572864, Cg);
    k_assemble<<<(BATCH * CELL_DIM * (NTOK / 4) + 255) / 256, 256, 0, stream>>>(cells, Cg, bh, outp);
}

// Round 4
// 431.646 us; speedup vs baseline: 3.4894x; 1.1429x over previous
//
#include <hip/hip_runtime.h>
#include <hip/hip_bf16.h>
#include <math.h>

#define HEADS 8
#define HEAD_DIM 32
#define DIM 256
#define MLP_DIM 1024
#define NTOK 4096
#define BATCH 8
#define M_TOK (BATCH*NTOK)
#define CELL_DIM 15
#define PE_IN 3
#define UPD 12
#define HME ((size_t)M_TOK*32)   // elements per head-plane [tok][32]

typedef __attribute__((ext_vector_type(8))) short bf16x8;
typedef __attribute__((ext_vector_type(4))) float f32x4;

static __device__ __forceinline__ float bf2f(unsigned short u) {
    return __uint_as_float(((unsigned int)u) << 16);
}
static __device__ __forceinline__ unsigned short f2bf(float f) {
    __hip_bfloat16 h = __float2bfloat16(f);
    union { __hip_bfloat16 h; unsigned short u; } cv; cv.h = h; return cv.u;
}
static __device__ __forceinline__ void gload_lds16(const unsigned short* g, unsigned short* l) {
    __builtin_amdgcn_global_load_lds(
        (const __attribute__((address_space(1))) void*)g,
        (__attribute__((address_space(3))) void*)l, 16, 0, 0);
}
static __device__ __forceinline__ float gelu_exact(float v) {
    return v * 0.5f * (1.f + erff(v * 0.70710678118f));
}

// embed + fused LN1[0]: x = cells@We + be + pe ; y = LN(x)
__global__ __launch_bounds__(256) void k_embed(const float* __restrict__ cells,
        const float* __restrict__ We, const float* __restrict__ be,
        const float* __restrict__ g, const float* __restrict__ bln,
        float* __restrict__ x, unsigned short* __restrict__ y) {
    __shared__ float red[8];
    int tok = blockIdx.x;
    int d = threadIdx.x;
    int b = tok >> 12, n = tok & 4095;
    const float* cb = cells + (size_t)b * CELL_DIM * NTOK + n;
    float acc = 0.f;
#pragma unroll
    for (int c = 0; c < CELL_DIM; ++c)
        acc += cb[c * NTOK] * We[c * DIM + d];
    int i = d >> 1;
    float freq = expf(-logf(10000.f) * (float)(2 * i) / (float)DIM);
    float ph = (float)n * freq;
    float pe = (d & 1) ? cosf(ph) : sinf(ph);
    float v = acc + be[d] + pe;
    x[(size_t)tok * DIM + d] = v;
    float s = v, ss = v * v;
#pragma unroll
    for (int off = 32; off; off >>= 1) { s += __shfl_xor(s, off); ss += __shfl_xor(ss, off); }
    int wave = d >> 6, lane = d & 63;
    if (lane == 0) { red[wave] = s; red[4 + wave] = ss; }
    __syncthreads();
    float stot = red[0] + red[1] + red[2] + red[3];
    float sstot = red[4] + red[5] + red[6] + red[7];
    float mean = stot * (1.f / DIM);
    float rstd = rsqrtf(sstot * (1.f / DIM) - mean * mean + 1e-5f);
    y[(size_t)tok * DIM + d] = f2bf((v - mean) * rstd * g[d] + bln[d]);
}

// Transpose+convert weights to bf16 [N,K]; seg 8 builds WhT [16x256] (rows 12-15 zero)
__global__ __launch_bounds__(256) void k_prep(const float* __restrict__ Wqkv,
        const float* __restrict__ Wo, const float* __restrict__ W1,
        const float* __restrict__ W2, const float* __restrict__ Wh,
        unsigned short* __restrict__ wT) {
    int seg = blockIdx.y;
    int idx = blockIdx.x * 256 + threadIdx.x;
    if (seg == 8) {
        if (idx >= 16 * 256) return;
        int u = idx >> 8, k = idx & 255;
        wT[1572864 + idx] = (u < UPD) ? f2bf(Wh[(size_t)k * UPD + u]) : (unsigned short)0;
        return;
    }
    int l = seg >> 2, mat = seg & 3;
    const float* src; int kwSh, Nw; size_t ooff;
    switch (mat) {
        case 0: src = Wqkv + (size_t)l * 196608; kwSh = 8;  Nw = 768;  ooff = (size_t)l * 786432 + 0;      break;
        case 1: src = Wo   + (size_t)l * 65536;  kwSh = 8;  Nw = 256;  ooff = (size_t)l * 786432 + 196608; break;
        case 2: src = W1   + (size_t)l * 262144; kwSh = 8;  Nw = 1024; ooff = (size_t)l * 786432 + 262144; break;
        default:src = W2   + (size_t)l * 262144; kwSh = 10; Nw = 256;  ooff = (size_t)l * 786432 + 524288; break;
    }
    int Kw = 1 << kwSh;
    if (idx >= Kw * Nw) return;
    int n = idx >> kwSh, k = idx & (Kw - 1);
    wT[ooff + idx] = f2bf(src[(size_t)k * Nw + n]);
}

// MFMA GEMM: C[M,N] = A[M,K](bf16) @ BT[N,K]^T + epi.
// EPI1: gelu(+bias)->bf16 [M,N] ; EPI3: qkv scatter to headwise [type][h][tok][32]
template<int EPI>
__global__ __launch_bounds__(256) void k_mgemm(const unsigned short* __restrict__ A,
        const unsigned short* __restrict__ BT, const float* __restrict__ bias,
        void* __restrict__ Cout, int M, int N, int K) {
    __shared__ unsigned short As[128 * 32];
    __shared__ unsigned short Bs[128 * 32];
    int t = threadIdx.x;
    int lane = t & 63, w = t >> 6;
    int wm = (w >> 1) * 64, wn = (w & 1) * 64;
    int m0 = blockIdx.y * 128, n0 = blockIdx.x * 128;

    f32x4 acc[4][4] = {};
    const unsigned short* aBase = A  + (size_t)(m0 + (t >> 2)) * K + (t & 3) * 8;
    const unsigned short* bBase = BT + (size_t)(n0 + (t >> 2)) * K + (t & 3) * 8;
    unsigned short* aDst = As + t * 8;
    unsigned short* bDst = Bs + t * 8;
    int fr = lane & 15, kb = (lane >> 4) * 8;

    for (int k0 = 0; k0 < K; k0 += 32) {
        gload_lds16(aBase + k0,          aDst);
        gload_lds16(aBase + 64 * K + k0, aDst + 2048);
        gload_lds16(bBase + k0,          bDst);
        gload_lds16(bBase + 64 * K + k0, bDst + 2048);
        __syncthreads();
        bf16x8 af[4], bfv[4];
#pragma unroll
        for (int i = 0; i < 4; ++i)
            af[i] = *(const bf16x8*)&As[(wm + i * 16 + fr) * 32 + kb];
#pragma unroll
        for (int j = 0; j < 4; ++j)
            bfv[j] = *(const bf16x8*)&Bs[(wn + j * 16 + fr) * 32 + kb];
#pragma unroll
        for (int i = 0; i < 4; ++i)
#pragma unroll
            for (int j = 0; j < 4; ++j)
                acc[i][j] = __builtin_amdgcn_mfma_f32_16x16x32_bf16(af[i], bfv[j], acc[i][j], 0, 0, 0);
        __syncthreads();
    }

    int col = lane & 15;
    int rowq = (lane >> 4) * 4;
#pragma unroll
    for (int j = 0; j < 4; ++j) {
        int gcol = n0 + wn + j * 16 + col;
        if (EPI == 3) {
            int type = gcol >> 8, rem = gcol & 255;
            size_t base = (size_t)(type * 8 + (rem >> 5)) * HME + (rem & 31);
#pragma unroll
            for (int i = 0; i < 4; ++i)
#pragma unroll
                for (int r = 0; r < 4; ++r) {
                    int grow = m0 + wm + i * 16 + rowq + r;
                    ((unsigned short*)Cout)[base + (size_t)grow * 32] = f2bf(acc[i][j][r]);
                }
        } else {
            float bv = bias ? bias[gcol] : 0.f;
#pragma unroll
            for (int i = 0; i < 4; ++i)
#pragma unroll
                for (int r = 0; r < 4; ++r) {
                    int grow = m0 + wm + i * 16 + rowq + r;
                    float v = acc[i][j][r] + bv;
                    if (EPI == 1) v = gelu_exact(v);
                    ((unsigned short*)Cout)[(size_t)grow * N + gcol] = f2bf(v);
                }
        }
    }
}

// Fused residual GEMM + LayerNorm, N==256. 512 threads, tile 128x256.
// ALAYOUT 0: A[M,K] row-major ; ALAYOUT 1: A headwise [8][M][32] (K=256)
// x = A@BT + bias + x ; y = LN(x; g,b)
template<int ALAYOUT>
__global__ __launch_bounds__(512) void k_mgemm_ln(const unsigned short* __restrict__ A,
        const unsigned short* __restrict__ BT, const float* __restrict__ bias,
        const float* __restrict__ g, const float* __restrict__ bln,
        float* __restrict__ x, unsigned short* __restrict__ y, int K) {
    __shared__ unsigned short As[128 * 32];
    __shared__ unsigned short Bs[256 * 32];
    __shared__ float sred[128 * 4];
    __shared__ float ssred[128 * 4];
    __shared__ float msr[128 * 2];
    int t = threadIdx.x;
    int lane = t & 63, w = t >> 6;
    int wm = (w >> 2) * 64, wn = (w & 3) * 64, wnq = w & 3;
    int m0 = blockIdx.x * 128;

    f32x4 acc[4][4] = {};
    const unsigned short* aBase = (ALAYOUT == 0)
        ? A + (size_t)(m0 + (t >> 2)) * K + (t & 3) * 8
        : A + (size_t)(m0 + (t >> 2)) * 32 + (t & 3) * 8;
    const unsigned short* bBase = BT + (size_t)(t >> 2) * K + (t & 3) * 8;
    unsigned short* aDst = As + t * 8;
    unsigned short* bDst = Bs + t * 8;
    int fr = lane & 15, kb = (lane >> 4) * 8;

    for (int k0 = 0; k0 < K; k0 += 32) {
        const unsigned short* aSrc = (ALAYOUT == 0) ? aBase + k0 : aBase + (size_t)(k0 >> 5) * HME;
        gload_lds16(aSrc,                 aDst);
        gload_lds16(bBase + k0,           bDst);
        gload_lds16(bBase + 128 * K + k0, bDst + 4096);
        __syncthreads();
        bf16x8 af[4], bfv[4];
#pragma unroll
        for (int i = 0; i < 4; ++i)
            af[i] = *(const bf16x8*)&As[(wm + i * 16 + fr) * 32 + kb];
#pragma unroll
        for (int j = 0; j < 4; ++j)
            bfv[j] = *(const bf16x8*)&Bs[(wn + j * 16 + fr) * 32 + kb];
#pragma unroll
        for (int i = 0; i < 4; ++i)
#pragma unroll
            for (int j = 0; j < 4; ++j)
                acc[i][j] = __builtin_amdgcn_mfma_f32_16x16x32_bf16(af[i], bfv[j], acc[i][j], 0, 0, 0);
        __syncthreads();
    }

    int col = lane & 15;
    int rowq = (lane >> 4) * 4;
    float bv[4];
#pragma unroll
    for (int j = 0; j < 4; ++j) bv[j] = bias[wn + j * 16 + col];
#pragma unroll
    for (int i = 0; i < 4; ++i)
#pragma unroll
        for (int r = 0; r < 4; ++r) {
            int grow = m0 + wm + i * 16 + rowq + r;
#pragma unroll
            for (int j = 0; j < 4; ++j)
                acc[i][j][r] += bv[j] + x[(size_t)grow * DIM + wn + j * 16 + col];
        }
#pragma unroll
    for (int i = 0; i < 4; ++i)
#pragma unroll
        for (int r = 0; r < 4; ++r) {
            float s = acc[i][0][r] + acc[i][1][r] + acc[i][2][r] + acc[i][3][r];
            float ss = acc[i][0][r] * acc[i][0][r] + acc[i][1][r] * acc[i][1][r]
                     + acc[i][2][r] * acc[i][2][r] + acc[i][3][r] * acc[i][3][r];
#pragma unroll
            for (int off = 1; off < 16; off <<= 1) { s += __shfl_xor(s, off); ss += __shfl_xor(ss, off); }
            if ((lane & 15) == 0) {
                int row = wm + i * 16 + rowq + r;
                sred[row * 4 + wnq] = s;
                ssred[row * 4 + wnq] = ss;
            }
        }
    __syncthreads();
    if (t < 128) {
        float s = sred[t * 4] + sred[t * 4 + 1] + sred[t * 4 + 2] + sred[t * 4 + 3];
        float ss = ssred[t * 4] + ssred[t * 4 + 1] + ssred[t * 4 + 2] + ssred[t * 4 + 3];
        float mean = s * (1.f / DIM);
        float var = ss * (1.f / DIM) - mean * mean;
        msr[t * 2] = mean;
        msr[t * 2 + 1] = rsqrtf(var + 1e-5f);
    }
    __syncthreads();
    float gv[4], bb[4];
#pragma unroll
    for (int j = 0; j < 4; ++j) { gv[j] = g[wn + j * 16 + col]; bb[j] = bln[wn + j * 16 + col]; }
#pragma unroll
    for (int i = 0; i < 4; ++i)
#pragma unroll
        for (int r = 0; r < 4; ++r) {
            int row = wm + i * 16 + rowq + r;
            int grow = m0 + row;
            float mean = msr[row * 2], rstd = msr[row * 2 + 1];
#pragma unroll
            for (int j = 0; j < 4; ++j) {
                float v = acc[i][j][r];
                int gcol = wn + j * 16 + col;
                x[(size_t)grow * DIM + gcol] = v;
                y[(size_t)grow * DIM + gcol] = f2bf((v - mean) * rstd * gv[j] + bb[j]);
            }
        }
}

// thread-per-(token,head) local 3x3 attention, headwise layout, no cross-lane ops.
// qkvH: [3][8][M][32] bf16 ; attnH out: [8][M][32] bf16
__global__ __launch_bounds__(256) void k_attn(const unsigned short* __restrict__ qkvH,
        unsigned short* __restrict__ attnH) {
    int t = threadIdx.x;
    int h = t >> 5, tl = t & 31;
    int tok = blockIdx.x * 32 + tl;
    int b = tok >> 12, n = tok & 4095;
    int r = n >> 6, c = n & 63;

    float q[32];
    {
        const uint4* u = (const uint4*)(qkvH + (size_t)h * HME + (size_t)tok * 32);
#pragma unroll
        for (int i = 0; i < 4; ++i) {
            uint4 x4 = u[i];
            unsigned wv[4] = {x4.x, x4.y, x4.z, x4.w};
#pragma unroll
            for (int wj = 0; wj < 4; ++wj) {
                q[i * 8 + wj * 2]     = __uint_as_float(wv[wj] << 16);
                q[i * 8 + wj * 2 + 1] = __uint_as_float(wv[wj] & 0xffff0000u);
            }
        }
    }
    int nts[9];
    float dots[9];
    const unsigned short* kbase = qkvH + (size_t)(8 + h) * HME;
#pragma unroll
    for (int ki = 0; ki < 3; ++ki)
#pragma unroll
        for (int kj = 0; kj < 3; ++kj) {
            int rr = (r + ki - 1) & 63, cc = (c + kj - 1) & 63;
            int nt = (b << 12) + (rr << 6) + cc;
            nts[ki * 3 + kj] = nt;
            const uint4* u = (const uint4*)(kbase + (size_t)nt * 32);
            float acc = 0.f;
#pragma unroll
            for (int i = 0; i < 4; ++i) {
                uint4 x4 = u[i];
                unsigned wv[4] = {x4.x, x4.y, x4.z, x4.w};
#pragma unroll
                for (int wj = 0; wj < 4; ++wj) {
                    acc += __uint_as_float(wv[wj] << 16)        * q[i * 8 + wj * 2];
                    acc += __uint_as_float(wv[wj] & 0xffff0000u) * q[i * 8 + wj * 2 + 1];
                }
            }
            dots[ki * 3 + kj] = acc * 0.17677669529f;
        }
    float m = dots[0];
#pragma unroll
    for (int j = 1; j < 9; ++j) m = fmaxf(m, dots[j]);
    float sum = 0.f;
#pragma unroll
    for (int j = 0; j < 9; ++j) { dots[j] = __expf(dots[j] - m); sum += dots[j]; }
    float inv = 1.f / sum;
    float o[32] = {};
    const unsigned short* vbase = qkvH + (size_t)(16 + h) * HME;
#pragma unroll
    for (int j = 0; j < 9; ++j) {
        float wgt = dots[j] * inv;
        const uint4* u = (const uint4*)(vbase + (size_t)nts[j] * 32);
#pragma unroll
        for (int i = 0; i < 4; ++i) {
            uint4 x4 = u[i];
            unsigned wv[4] = {x4.x, x4.y, x4.z, x4.w};
#pragma unroll
            for (int wj = 0; wj < 4; ++wj) {
                o[i * 8 + wj * 2]     += wgt * __uint_as_float(wv[wj] << 16);
                o[i * 8 + wj * 2 + 1] += wgt * __uint_as_float(wv[wj] & 0xffff0000u);
            }
        }
    }
    uint4 st[4];
    unsigned* sw = (unsigned*)st;
#pragma unroll
    for (int i = 0; i < 16; ++i)
        sw[i] = (unsigned)f2bf(o[2 * i]) | ((unsigned)f2bf(o[2 * i + 1]) << 16);
    uint4* od = (uint4*)(attnH + (size_t)h * HME + (size_t)tok * 32);
#pragma unroll
    for (int i = 0; i < 4; ++i) od[i] = st[i];
}

// head GEMV via MFMA: Cg[32768,16] = y[32768,256] @ WhT[16,256]^T
__global__ __launch_bounds__(256) void k_headgemv(const unsigned short* __restrict__ y,
        const unsigned short* __restrict__ WhT, float* __restrict__ Cg) {
    int t = threadIdx.x, lane = t & 63, w = t >> 6;
    int m0 = blockIdx.x * 64 + w * 16;
    int fr = lane & 15, kb = (lane >> 4) * 8;
    f32x4 acc = {};
    const unsigned short* aRow = y + (size_t)(m0 + fr) * DIM + kb;
    const unsigned short* bRow = WhT + (size_t)fr * DIM + kb;
#pragma unroll
    for (int k0 = 0; k0 < DIM; k0 += 32) {
        bf16x8 a = *(const bf16x8*)(aRow + k0);
        bf16x8 bfr = *(const bf16x8*)(bRow + k0);
        acc = __builtin_amdgcn_mfma_f32_16x16x32_bf16(a, bfr, acc, 0, 0, 0);
    }
    int col = lane & 15, rowq = (lane >> 4) * 4;
#pragma unroll
    for (int r = 0; r < 4; ++r)
        Cg[(size_t)(m0 + rowq + r) * 16 + col] = acc[r];
}

// out[b,c,n] = cells[b,c,n] + (c>=3 ? Cg[tok,c-3] + bh[c-3] : 0)
__global__ __launch_bounds__(256) void k_assemble(const float* __restrict__ cells,
        const float* __restrict__ Cg, const float* __restrict__ bh,
        float* __restrict__ outp) {
    int idx = blockIdx.x * 256 + threadIdx.x;
    int total = BATCH * CELL_DIM * (NTOK / 4);
    if (idx >= total) return;
    int n4 = idx & 1023;
    int c = (idx >> 10) % CELL_DIM;
    int b = idx / (CELL_DIM * 1024);
    size_t ci = ((size_t)b * CELL_DIM + c) * NTOK + n4 * 4;
    float4 o = *(const float4*)(cells + ci);
    if (c >= PE_IN) {
        int u = c - PE_IN;
        float bias = bh[u];
        size_t tok = (size_t)b * NTOK + n4 * 4;
        o.x += Cg[(tok + 0) * 16 + u] + bias;
        o.y += Cg[(tok + 1) * 16 + u] + bias;
        o.z += Cg[(tok + 2) * 16 + u] + bias;
        o.w += Cg[(tok + 3) * 16 + u] + bias;
    }
    *(float4*)(outp + ci) = o;
}

extern "C" void kernel_launch(void* const* d_in, const int* in_sizes, int n_in,
                              void* d_out, int out_size, void* d_ws, size_t ws_size,
                              hipStream_t stream) {
    const float* cells = (const float*)d_in[0];
    const float* We    = (const float*)d_in[1];
    const float* be    = (const float*)d_in[2];
    const float* ln1_g = (const float*)d_in[3];
    const float* ln1_b = (const float*)d_in[4];
    const float* Wqkv  = (const float*)d_in[5];
    const float* Wo    = (const float*)d_in[6];
    const float* bo    = (const float*)d_in[7];
    const float* ln2_g = (const float*)d_in[8];
    const float* ln2_b = (const float*)d_in[9];
    const float* W1    = (const float*)d_in[10];
    const float* b1    = (const float*)d_in[11];
    const float* W2    = (const float*)d_in[12];
    const float* b2    = (const float*)d_in[13];
    const float* lnh_g = (const float*)d_in[14];
    const float* lnh_b = (const float*)d_in[15];
    const float* Wh    = (const float*)d_in[16];
    const float* bh    = (const float*)d_in[17];
    float* outp = (float*)d_out;

    char* ws = (char*)d_ws;
    float* x = (float*)ws;                                        // 33.5 MB f32 residual
    unsigned short* y = (unsigned short*)(ws + 33554432);         // 16.8 MB bf16 LN-out
    unsigned short* scratch = (unsigned short*)(ws + 50331648);   // 67 MB: qkvH+attnH / hidden / Cg
    unsigned short* wT = (unsigned short*)(ws + 117440512);       // 3 MB + 8KB transposed weights
    unsigned short* qkvH  = scratch;                              // [3][8][M][32] = 50.3 MB
    unsigned short* attnH = scratch + 24 * HME;                   // [8][M][32]   = 16.8 MB
    unsigned short* hidden = scratch;                             // reuse (qkv dead by mlp1)
    float* Cg = (float*)scratch;                                  // reuse after last mlp2

    k_prep<<<dim3(1024, 9), 256, 0, stream>>>(Wqkv, Wo, W1, W2, Wh, wT);
    k_embed<<<M_TOK, 256, 0, stream>>>(cells, We, be, ln1_g, ln1_b, x, y);
    for (int l = 0; l < 2; ++l) {
        const unsigned short* wL = wT + (size_t)l * 786432;
        const float* gN = (l == 0) ? ln1_g + DIM : lnh_g;
        const float* bN = (l == 0) ? ln1_b + DIM : lnh_b;
        k_mgemm<3><<<dim3(6, M_TOK / 128), 256, 0, stream>>>(
            y, wL + 0, nullptr, qkvH, M_TOK, 768, DIM);
        k_attn<<<M_TOK / 32, 256, 0, stream>>>(qkvH, attnH);
        k_mgemm_ln<1><<<M_TOK / 128, 512, 0, stream>>>(
            attnH, wL + 196608, bo + l * DIM, ln2_g + l * DIM, ln2_b + l * DIM, x, y, DIM);
        k_mgemm<1><<<dim3(8, M_TOK / 128), 256, 0, stream>>>(
            y, wL + 262144, b1 + l * MLP_DIM, hidden, M_TOK, MLP_DIM, DIM);
        k_mgemm_ln<0><<<M_TOK / 128, 512, 0, stream>>>(
            hidden, wL + 524288, b2 + l * DIM, gN, bN, x, y, MLP_DIM);
    }
    k_headgemv<<<M_TOK / 64, 256, 0, stream>>>(y, wT + 1572864, Cg);
    k_assemble<<<(BATCH * CELL_DIM * (NTOK / 4) + 255) / 256, 256, 0, stream>>>(cells, Cg, bh, outp);
}